// Round 1
// baseline (604.746 us; speedup 1.0000x reference)
//
#include <hip/hip_runtime.h>
#include <hip/hip_bf16.h>
#include <stdint.h>

// ---------------- problem constants ----------------
constexpr int   SEQ  = 8192;
constexpr int   NB   = 64;
constexpr int   ND   = 16;
constexpr float DT    = 0.01f;
constexpr float BETA  = 0.25f;
constexpr float GAMMA = 0.5f;
constexpr float C1 = (0.5f - BETA) * DT * DT;   // u_pred coeff on a
constexpr float C2 = (1.0f - GAMMA) * DT;       // v_pred coeff on a
constexpr float C3 = BETA * DT * DT;            // u_n  = up + C3*a
constexpr float C4 = GAMMA * DT;                // v_n  = vp + C4*a
constexpr float E1 = C1 + C3 + DT * C4;         // up' = up + DT*vp + E1*a
constexpr float E2 = C2 + C4;                   // vp' = vp + E2*a
constexpr float GDT  = GAMMA * DT;
constexpr float BDT2 = BETA * DT * DT;

constexpr int L  = 16;     // steps per chunk
constexpr int NC = 512;    // chunks  (NC*L = SEQ)
constexpr size_t BSTRIDE = (size_t)SEQ * ND;        // 131072
constexpr size_t UOFF = 0;
constexpr size_t VOFF = (size_t)NB * SEQ * ND;      // 8388608
constexpr size_t AOFF = 2 * VOFF;                   // 16777216

// ws layout (float offsets)
constexpr int WS_A1T  = 0;      // 256  (transposed: A1t[j*16+d] = A1[d][j])
constexpr int WS_A2T  = 256;
constexpr int WS_A3T  = 512;
constexpr int WS_G16  = 768;    // 1024, row-major 32x32
constexpr int WS_G512 = 1792;   // 1024
constexpr int WS_P1   = 2816;   // 2048  p1[r*64+b]
constexpr int WS_D    = 4864;   // 16*2048 super-chunk buffer
constexpr int WS_C    = 37632;  // 512*2048 chunk totals -> later p_starts

// =====================================================================
// K0: matrices, powers, a0 / p1 / step-0 outputs.  1 block x 512 thr.
// =====================================================================
__global__ __launch_bounds__(512) void setup_k(const float* __restrict__ F,
                                               const float* __restrict__ Mg,
                                               const float* __restrict__ Cg,
                                               const float* __restrict__ Kg,
                                               float* __restrict__ ws,
                                               float* __restrict__ out)
{
    __shared__ float sM[256], sC[256], sK[256];
    __shared__ float aug[16][33];
    __shared__ float A1s[256], A2s[256], A3s[256], Mis[256];
    __shared__ float bA[1024], bB[1024];
    const int tid = threadIdx.x;
    if (tid < 256) { sM[tid] = Mg[tid]; sC[tid] = Cg[tid]; sK[tid] = Kg[tid]; }
    __syncthreads();

    const int r = tid >> 5, c = tid & 31;   // 16 x 32 = 512 threads exactly
    // ---- Gauss-Jordan invert K_eff = M + GDT*C + BDT2*K ----
    {
        float v;
        if (c < 16) v = sM[r*16+c] + GDT * sC[r*16+c] + BDT2 * sK[r*16+c];
        else        v = (c - 16 == r) ? 1.f : 0.f;
        aug[r][c] = v;
    }
    __syncthreads();
    for (int kk = 0; kk < 16; ++kk) {
        float pv   = aug[kk][kk];
        float fr   = aug[r][kk];
        float akc  = aug[kk][c];
        float curv = aug[r][c];
        __syncthreads();
        float inv = 1.0f / pv;
        aug[r][c] = (r == kk) ? curv * inv : fmaf(-fr * inv, akc, curv);
        __syncthreads();
    }
    if (tid < 256) A1s[tid] = aug[tid >> 4][(tid & 15) + 16];
    __syncthreads();

    // ---- Gauss-Jordan invert M ----
    aug[r][c] = (c < 16) ? sM[r*16+c] : ((c - 16 == r) ? 1.f : 0.f);
    __syncthreads();
    for (int kk = 0; kk < 16; ++kk) {
        float pv   = aug[kk][kk];
        float fr   = aug[r][kk];
        float akc  = aug[kk][c];
        float curv = aug[r][c];
        __syncthreads();
        float inv = 1.0f / pv;
        aug[r][c] = (r == kk) ? curv * inv : fmaf(-fr * inv, akc, curv);
        __syncthreads();
    }
    if (tid < 256) Mis[tid] = aug[tid >> 4][(tid & 15) + 16];
    __syncthreads();

    // ---- A2 = A1*C , A3 = A1*K ----
    if (tid < 256) {
        const int rr = tid >> 4, cc = tid & 15;
        float a2 = 0.f, a3 = 0.f;
        #pragma unroll
        for (int j = 0; j < 16; ++j) {
            const float a = A1s[rr*16+j];
            a2 = fmaf(a, sC[j*16+cc], a2);
            a3 = fmaf(a, sK[j*16+cc], a3);
        }
        A2s[tid] = a2; A3s[tid] = a3;
    }
    __syncthreads();

    // ---- store transposed A's ----
    if (tid < 256) {
        const int j = tid >> 4, d = tid & 15;
        ws[WS_A1T + tid] = A1s[d*16+j];
        ws[WS_A2T + tid] = A2s[d*16+j];
        ws[WS_A3T + tid] = A3s[d*16+j];
    }
    // ---- build G (32x32) ----
    for (int idx = tid; idx < 1024; idx += 512) {
        const int i = idx >> 5, j = idx & 31;
        float v;
        if (i < 16) {
            if (j < 16) v = ((i == j) ? 1.f : 0.f) - E1 * A3s[i*16+j];
            else        v = ((i == j - 16) ? DT : 0.f) - E1 * A2s[i*16+(j-16)];
        } else {
            const int i2 = i - 16;
            if (j < 16) v = -E2 * A3s[i2*16+j];
            else        v = ((i2 == j - 16) ? 1.f : 0.f) - E2 * A2s[i2*16+(j-16)];
        }
        bA[idx] = v;
    }
    __syncthreads();
    // ---- 9 squarings: G^2..G^16 (store) ..G^512 (store) ----
    for (int s = 0; s < 9; ++s) {
        for (int idx = tid; idx < 1024; idx += 512) {
            const int i = idx >> 5, j = idx & 31;
            float acc = 0.f;
            #pragma unroll
            for (int q = 0; q < 32; ++q) acc = fmaf(bA[i*32+q], bA[q*32+j], acc);
            bB[idx] = acc;
        }
        __syncthreads();
        for (int idx = tid; idx < 1024; idx += 512) bA[idx] = bB[idx];
        __syncthreads();
        if (s == 3) for (int idx = tid; idx < 1024; idx += 512) ws[WS_G16 + idx] = bA[idx];
    }
    for (int idx = tid; idx < 1024; idx += 512) ws[WS_G512 + idx] = bA[idx];

    // ---- a0 = Minv * F[:,0,:], p1 seed, step-0 outputs ----
    for (int t = tid; t < 1024; t += 512) {
        const int b = t >> 4, d = t & 15;
        float s0 = 0.f;
        #pragma unroll
        for (int j = 0; j < 16; ++j) s0 = fmaf(Mis[d*16+j], F[(size_t)b * BSTRIDE + j], s0);
        out[UOFF + (size_t)b * BSTRIDE + d] = 0.f;
        out[VOFF + (size_t)b * BSTRIDE + d] = 0.f;
        out[AOFF + (size_t)b * BSTRIDE + d] = s0;
        ws[WS_P1 + d*64 + b]        = C1 * s0;
        ws[WS_P1 + (16 + d)*64 + b] = C2 * s0;
    }
}

// ---------------------------------------------------------------------
// one Newmark step's acceleration matvec: acc = A1*f - A3*up - A2*vp
// (matrices stored transposed; wave-uniform -> s_load + v_fmac)
// ---------------------------------------------------------------------
__device__ __forceinline__ void step_matvec(const float* A1t, const float* A2t, const float* A3t,
                                            const float f[16], const float up[16], const float vp[16],
                                            float acc[16])
{
    #pragma unroll
    for (int d = 0; d < 16; ++d) acc[d] = 0.f;
    #pragma unroll
    for (int j = 0; j < 16; ++j) {
        const float fj = f[j], nu = -up[j], nv = -vp[j];
        #pragma unroll
        for (int d = 0; d < 16; ++d) {
            acc[d] = fmaf(A1t[j*16+d], fj, acc[d]);
            acc[d] = fmaf(A3t[j*16+d], nu, acc[d]);
            acc[d] = fmaf(A2t[j*16+d], nv, acc[d]);
        }
    }
}

// =====================================================================
// K1: per-chunk totals from zero state.  grid NC x 64, lane = batch.
// =====================================================================
__global__ __launch_bounds__(64) void phase1_k(const float* __restrict__ F,
                                               const float* ws_in,
                                               float* __restrict__ cbuf)
{
    const int b = threadIdx.x;
    const int k = blockIdx.x;
    float up[16], vp[16];
    #pragma unroll
    for (int d = 0; d < 16; ++d) { up[d] = 0.f; vp[d] = 0.f; }
    const float* Fb = F + (size_t)b * BSTRIDE + (size_t)(L * k + 1) * ND;
    const int nsteps = min(L, SEQ - 1 - L * k);
    const uintptr_t wsa = (uintptr_t)ws_in;
    for (int i = 0; i < nsteps; ++i) {
        uintptr_t wsl = wsa;
        asm volatile("" : "+s"(wsl));            // defeat LICM: reload matrices per step via s_load
        const float* __restrict__ A1t = (const float*)wsl;
        const float* __restrict__ A2t = A1t + 256;
        const float* __restrict__ A3t = A1t + 512;
        const float4* fp = (const float4*)(Fb + (size_t)i * ND);
        const float4 f0 = fp[0], f1 = fp[1], f2 = fp[2], f3 = fp[3];
        const float f[16] = {f0.x,f0.y,f0.z,f0.w, f1.x,f1.y,f1.z,f1.w,
                             f2.x,f2.y,f2.z,f2.w, f3.x,f3.y,f3.z,f3.w};
        float acc[16];
        step_matvec(A1t, A2t, A3t, f, up, vp, acc);
        #pragma unroll
        for (int d = 0; d < 16; ++d) {
            up[d] = fmaf(DT, vp[d], up[d]);
            up[d] = fmaf(E1, acc[d], up[d]);
            vp[d] = fmaf(E2, acc[d], vp[d]);
        }
    }
    float* cs = cbuf + (size_t)k * 2048;
    #pragma unroll
    for (int d = 0; d < 16; ++d) { cs[d*64 + b] = up[d]; cs[(16 + d)*64 + b] = vp[d]; }
}

// =====================================================================
// K2: affine scan  p' = Gm*p + c_k  over nIter slots per block.
//  seed  == nullptr -> zero seed              (2a)
//  totals!= nullptr -> store final to totals  (2a)
//  totals== nullptr -> store p into slot k BEFORE update (in-place starts, 2b/2c)
//  block: 256 threads = 4 waves; wave w owns rows w+4q (q=0..7); lane = batch.
// =====================================================================
__global__ __launch_bounds__(256) void scan_k(const float* Gm_in,
                                              float* __restrict__ cbase,
                                              const float* __restrict__ seed,
                                              float* __restrict__ totals,
                                              int nIter)
{
    __shared__ float pb[2][2048];
    const int tid = threadIdx.x;
    const int b = tid & 63;
    const int w = __builtin_amdgcn_readfirstlane((int)(tid >> 6));   // 0..3, wave-uniform
    const int g = blockIdx.x;
    const uintptr_t ga = (uintptr_t)Gm_in;
    float pr[8];
    #pragma unroll
    for (int q = 0; q < 8; ++q) {
        const int rrow = w + 4*q;
        pr[q] = seed ? seed[(size_t)g * 2048 + rrow*64 + b] : 0.f;
        pb[0][rrow*64 + b] = pr[q];
    }
    __syncthreads();
    int cur = 0;
    float* cslot = cbase + (size_t)g * nIter * 2048;
    for (int k = 0; k < nIter; ++k) {
        uintptr_t gl = ga;
        asm volatile("" : "+s"(gl));
        const float* __restrict__ Gm = (const float*)gl;
        float n[8];
        #pragma unroll
        for (int q = 0; q < 8; ++q) n[q] = cslot[(w + 4*q)*64 + b];
        if (!totals) {
            #pragma unroll
            for (int q = 0; q < 8; ++q) cslot[(w + 4*q)*64 + b] = pr[q];
        }
        const float* prow = pb[cur];
        #pragma unroll
        for (int j = 0; j < 32; ++j) {
            const float pj = prow[j*64 + b];
            #pragma unroll
            for (int q = 0; q < 8; ++q)
                n[q] = fmaf(Gm[(w + 4*q)*32 + j], pj, n[q]);
        }
        #pragma unroll
        for (int q = 0; q < 8; ++q) { pr[q] = n[q]; pb[cur ^ 1][(w + 4*q)*64 + b] = n[q]; }
        cur ^= 1;
        cslot += 2048;
        __syncthreads();
    }
    if (totals) {
        #pragma unroll
        for (int q = 0; q < 8; ++q) totals[(size_t)g * 2048 + (w + 4*q)*64 + b] = pr[q];
    }
}

// =====================================================================
// K3: re-run chunks from scanned starts, emit u/v/a.  grid NC x 64.
// =====================================================================
__global__ __launch_bounds__(64) void phase3_k(const float* __restrict__ F,
                                               const float* ws_in,
                                               const float* __restrict__ starts,
                                               float* __restrict__ out)
{
    const int b = threadIdx.x;
    const int k = blockIdx.x;
    float up[16], vp[16];
    const float* st = starts + (size_t)k * 2048;
    #pragma unroll
    for (int d = 0; d < 16; ++d) { up[d] = st[d*64 + b]; vp[d] = st[(16 + d)*64 + b]; }
    const int nsteps = min(L, SEQ - 1 - L * k);
    const size_t base = (size_t)b * BSTRIDE + (size_t)(L * k + 1) * ND;
    const uintptr_t wsa = (uintptr_t)ws_in;
    for (int i = 0; i < nsteps; ++i) {
        uintptr_t wsl = wsa;
        asm volatile("" : "+s"(wsl));
        const float* __restrict__ A1t = (const float*)wsl;
        const float* __restrict__ A2t = A1t + 256;
        const float* __restrict__ A3t = A1t + 512;
        const float4* fp = (const float4*)(F + base + (size_t)i * ND);
        const float4 f0 = fp[0], f1 = fp[1], f2 = fp[2], f3 = fp[3];
        const float f[16] = {f0.x,f0.y,f0.z,f0.w, f1.x,f1.y,f1.z,f1.w,
                             f2.x,f2.y,f2.z,f2.w, f3.x,f3.y,f3.z,f3.w};
        float acc[16];
        step_matvec(A1t, A2t, A3t, f, up, vp, acc);
        float uo[16], vo[16];
        #pragma unroll
        for (int d = 0; d < 16; ++d) {
            uo[d] = fmaf(C3, acc[d], up[d]);
            vo[d] = fmaf(C4, acc[d], vp[d]);
        }
        float4* pu = (float4*)(out + UOFF + base + (size_t)i * ND);
        float4* pv = (float4*)(out + VOFF + base + (size_t)i * ND);
        float4* pa = (float4*)(out + AOFF + base + (size_t)i * ND);
        pu[0] = make_float4(uo[0],  uo[1],  uo[2],  uo[3]);
        pu[1] = make_float4(uo[4],  uo[5],  uo[6],  uo[7]);
        pu[2] = make_float4(uo[8],  uo[9],  uo[10], uo[11]);
        pu[3] = make_float4(uo[12], uo[13], uo[14], uo[15]);
        pv[0] = make_float4(vo[0],  vo[1],  vo[2],  vo[3]);
        pv[1] = make_float4(vo[4],  vo[5],  vo[6],  vo[7]);
        pv[2] = make_float4(vo[8],  vo[9],  vo[10], vo[11]);
        pv[3] = make_float4(vo[12], vo[13], vo[14], vo[15]);
        pa[0] = make_float4(acc[0],  acc[1],  acc[2],  acc[3]);
        pa[1] = make_float4(acc[4],  acc[5],  acc[6],  acc[7]);
        pa[2] = make_float4(acc[8],  acc[9],  acc[10], acc[11]);
        pa[3] = make_float4(acc[12], acc[13], acc[14], acc[15]);
        #pragma unroll
        for (int d = 0; d < 16; ++d) {
            up[d] = fmaf(DT, vp[d], up[d]);
            up[d] = fmaf(E1, acc[d], up[d]);
            vp[d] = fmaf(E2, acc[d], vp[d]);
        }
    }
}

// =====================================================================
extern "C" void kernel_launch(void* const* d_in, const int* in_sizes, int n_in,
                              void* d_out, int out_size, void* d_ws, size_t ws_size,
                              hipStream_t stream)
{
    const float* F = (const float*)d_in[0];
    const float* M = (const float*)d_in[1];
    const float* C = (const float*)d_in[2];
    const float* K = (const float*)d_in[3];
    float* out = (float*)d_out;
    float* ws  = (float*)d_ws;

    setup_k <<<1,   512, 0, stream>>>(F, M, C, K, ws, out);
    phase1_k<<<NC,  64,  0, stream>>>(F, ws, ws + WS_C);
    scan_k  <<<16,  256, 0, stream>>>(ws + WS_G16,  ws + WS_C, nullptr,      ws + WS_D, 32);
    scan_k  <<<1,   256, 0, stream>>>(ws + WS_G512, ws + WS_D, ws + WS_P1,   nullptr,   16);
    scan_k  <<<16,  256, 0, stream>>>(ws + WS_G16,  ws + WS_C, ws + WS_D,    nullptr,   32);
    phase3_k<<<NC,  64,  0, stream>>>(F, ws, ws + WS_C, out);
}

// Round 2
// 572.197 us; speedup vs baseline: 1.0569x; 1.0569x over previous
//
#include <hip/hip_runtime.h>
#include <hip/hip_bf16.h>
#include <stdint.h>

// ---------------- problem constants ----------------
constexpr int   SEQ  = 8192;
constexpr int   NB   = 64;
constexpr int   ND   = 16;
constexpr float DT    = 0.01f;
constexpr float BETA  = 0.25f;
constexpr float GAMMA = 0.5f;
constexpr float C1 = (0.5f - BETA) * DT * DT;
constexpr float C2 = (1.0f - GAMMA) * DT;
constexpr float C3 = BETA * DT * DT;
constexpr float C4 = GAMMA * DT;
constexpr float E1 = C1 + C3 + DT * C4;
constexpr float E2 = C2 + C4;
constexpr float GDT  = GAMMA * DT;
constexpr float BDT2 = BETA * DT * DT;

constexpr int LSUB = 4;      // sub-chunk (phase1 wave / phase3 block granularity)
constexpr int LCH  = 16;     // chunk (scan granularity)
constexpr int NCH  = 512;    // chunks (NCH*LCH = SEQ)
constexpr size_t BSTRIDE = (size_t)SEQ * ND;
constexpr size_t UOFF = 0;
constexpr size_t VOFF = (size_t)NB * SEQ * ND;
constexpr size_t AOFF = 2 * VOFF;

// ws layout (float offsets) — total ~1.2M floats = 4.8 MB
constexpr int WS_A1T   = 0;       // 256 (transposed)
constexpr int WS_A2T   = 256;
constexpr int WS_A3T   = 512;
constexpr int WS_G4    = 768;     // 1024 each, row-major 32x32
constexpr int WS_G16   = 1792;
constexpr int WS_G128  = 2816;
constexpr int WS_G1024 = 3840;
constexpr int WS_P1    = 4864;    // 2048
constexpr int WS_ST    = 6912;    // 8   * 2048 super totals->starts
constexpr int WS_GT    = 23296;   // 64  * 2048 group totals->starts
constexpr int WS_C     = 154368;  // 512 * 2048 chunk totals->starts

// =====================================================================
// K0: invert K_eff & M, A2/A3, G powers, p1 seed, step-0 outputs.
// =====================================================================
__global__ __launch_bounds__(512) void setup_k(const float* __restrict__ F,
                                               const float* __restrict__ Mg,
                                               const float* __restrict__ Cg,
                                               const float* __restrict__ Kg,
                                               float* __restrict__ ws,
                                               float* __restrict__ out)
{
    __shared__ float sM[256], sC[256], sK[256];
    __shared__ float aug[16][33];
    __shared__ float A1s[256], A2s[256], A3s[256], Mis[256];
    __shared__ float bA[1024], bB[1024];
    const int tid = threadIdx.x;
    if (tid < 256) { sM[tid] = Mg[tid]; sC[tid] = Cg[tid]; sK[tid] = Kg[tid]; }
    __syncthreads();

    const int r = tid >> 5, c = tid & 31;
    // ---- invert K_eff ----
    {
        float v;
        if (c < 16) v = sM[r*16+c] + GDT * sC[r*16+c] + BDT2 * sK[r*16+c];
        else        v = (c - 16 == r) ? 1.f : 0.f;
        aug[r][c] = v;
    }
    __syncthreads();
    for (int kk = 0; kk < 16; ++kk) {
        float pv   = aug[kk][kk];
        float fr   = aug[r][kk];
        float akc  = aug[kk][c];
        float curv = aug[r][c];
        __syncthreads();
        float inv = 1.0f / pv;
        aug[r][c] = (r == kk) ? curv * inv : fmaf(-fr * inv, akc, curv);
        __syncthreads();
    }
    if (tid < 256) A1s[tid] = aug[tid >> 4][(tid & 15) + 16];
    __syncthreads();

    // ---- invert M ----
    aug[r][c] = (c < 16) ? sM[r*16+c] : ((c - 16 == r) ? 1.f : 0.f);
    __syncthreads();
    for (int kk = 0; kk < 16; ++kk) {
        float pv   = aug[kk][kk];
        float fr   = aug[r][kk];
        float akc  = aug[kk][c];
        float curv = aug[r][c];
        __syncthreads();
        float inv = 1.0f / pv;
        aug[r][c] = (r == kk) ? curv * inv : fmaf(-fr * inv, akc, curv);
        __syncthreads();
    }
    if (tid < 256) Mis[tid] = aug[tid >> 4][(tid & 15) + 16];
    __syncthreads();

    // ---- A2 = A1*C , A3 = A1*K ----
    if (tid < 256) {
        const int rr = tid >> 4, cc = tid & 15;
        float a2 = 0.f, a3 = 0.f;
        #pragma unroll
        for (int j = 0; j < 16; ++j) {
            const float a = A1s[rr*16+j];
            a2 = fmaf(a, sC[j*16+cc], a2);
            a3 = fmaf(a, sK[j*16+cc], a3);
        }
        A2s[tid] = a2; A3s[tid] = a3;
    }
    __syncthreads();

    if (tid < 256) {
        const int j = tid >> 4, d = tid & 15;
        ws[WS_A1T + tid] = A1s[d*16+j];
        ws[WS_A2T + tid] = A2s[d*16+j];
        ws[WS_A3T + tid] = A3s[d*16+j];
    }
    // ---- build G ----
    for (int idx = tid; idx < 1024; idx += 512) {
        const int i = idx >> 5, j = idx & 31;
        float v;
        if (i < 16) {
            if (j < 16) v = ((i == j) ? 1.f : 0.f) - E1 * A3s[i*16+j];
            else        v = ((i == j - 16) ? DT : 0.f) - E1 * A2s[i*16+(j-16)];
        } else {
            const int i2 = i - 16;
            if (j < 16) v = -E2 * A3s[i2*16+j];
            else        v = ((i2 == j - 16) ? 1.f : 0.f) - E2 * A2s[i2*16+(j-16)];
        }
        bA[idx] = v;
    }
    __syncthreads();
    // ---- 10 squarings: store G^4, G^16, G^128, G^1024 ----
    for (int s = 0; s < 10; ++s) {
        for (int idx = tid; idx < 1024; idx += 512) {
            const int i = idx >> 5, j = idx & 31;
            float acc = 0.f;
            #pragma unroll
            for (int q = 0; q < 32; ++q) acc = fmaf(bA[i*32+q], bA[q*32+j], acc);
            bB[idx] = acc;
        }
        __syncthreads();
        for (int idx = tid; idx < 1024; idx += 512) bA[idx] = bB[idx];
        __syncthreads();
        if (s == 1) for (int idx = tid; idx < 1024; idx += 512) ws[WS_G4   + idx] = bA[idx];
        if (s == 3) for (int idx = tid; idx < 1024; idx += 512) ws[WS_G16  + idx] = bA[idx];
        if (s == 6) for (int idx = tid; idx < 1024; idx += 512) ws[WS_G128 + idx] = bA[idx];
    }
    for (int idx = tid; idx < 1024; idx += 512) ws[WS_G1024 + idx] = bA[idx];

    // ---- a0 = Minv*F[:,0,:], p1 seed, step-0 outputs ----
    for (int t = tid; t < 1024; t += 512) {
        const int b = t >> 4, d = t & 15;
        float s0 = 0.f;
        #pragma unroll
        for (int j = 0; j < 16; ++j) s0 = fmaf(Mis[d*16+j], F[(size_t)b * BSTRIDE + j], s0);
        out[UOFF + (size_t)b * BSTRIDE + d] = 0.f;
        out[VOFF + (size_t)b * BSTRIDE + d] = 0.f;
        out[AOFF + (size_t)b * BSTRIDE + d] = s0;
        ws[WS_P1 + d*64 + b]        = C1 * s0;
        ws[WS_P1 + (16 + d)*64 + b] = C2 * s0;
    }
}

// ---------------------------------------------------------------------
// one Newmark step. Matrices wave-uniform (s_load via anti-LICM asm).
// STORE: also emit u/v/a for this step.
// ---------------------------------------------------------------------
template<bool STORE>
__device__ __forceinline__ void newmark_step(uintptr_t wsa, const float* __restrict__ fptr,
                                             float up[16], float vp[16],
                                             float* __restrict__ us, float* __restrict__ vs,
                                             float* __restrict__ as)
{
    uintptr_t wsl = wsa;
    asm volatile("" : "+s"(wsl));            // defeat LICM: reload matrices via s_load
    const float* __restrict__ A1t = (const float*)wsl;
    const float* __restrict__ A2t = A1t + 256;
    const float* __restrict__ A3t = A1t + 512;
    const float4* fp = (const float4*)fptr;
    const float4 f0 = fp[0], f1 = fp[1], f2 = fp[2], f3 = fp[3];
    const float f[16] = {f0.x,f0.y,f0.z,f0.w, f1.x,f1.y,f1.z,f1.w,
                         f2.x,f2.y,f2.z,f2.w, f3.x,f3.y,f3.z,f3.w};
    float acc[16];
    #pragma unroll
    for (int d = 0; d < 16; ++d) acc[d] = 0.f;
    #pragma unroll
    for (int j = 0; j < 16; ++j) {
        const float fj = f[j], nu = -up[j], nv = -vp[j];
        #pragma unroll
        for (int d = 0; d < 16; ++d) {
            acc[d] = fmaf(A1t[j*16+d], fj, acc[d]);
            acc[d] = fmaf(A3t[j*16+d], nu, acc[d]);
            acc[d] = fmaf(A2t[j*16+d], nv, acc[d]);
        }
    }
    if (STORE) {
        float uo[16], vo[16];
        #pragma unroll
        for (int d = 0; d < 16; ++d) {
            uo[d] = fmaf(C3, acc[d], up[d]);
            vo[d] = fmaf(C4, acc[d], vp[d]);
        }
        float4* pu = (float4*)us; float4* pv = (float4*)vs; float4* pa = (float4*)as;
        pu[0] = make_float4(uo[0],  uo[1],  uo[2],  uo[3]);
        pu[1] = make_float4(uo[4],  uo[5],  uo[6],  uo[7]);
        pu[2] = make_float4(uo[8],  uo[9],  uo[10], uo[11]);
        pu[3] = make_float4(uo[12], uo[13], uo[14], uo[15]);
        pv[0] = make_float4(vo[0],  vo[1],  vo[2],  vo[3]);
        pv[1] = make_float4(vo[4],  vo[5],  vo[6],  vo[7]);
        pv[2] = make_float4(vo[8],  vo[9],  vo[10], vo[11]);
        pv[3] = make_float4(vo[12], vo[13], vo[14], vo[15]);
        pa[0] = make_float4(acc[0],  acc[1],  acc[2],  acc[3]);
        pa[1] = make_float4(acc[4],  acc[5],  acc[6],  acc[7]);
        pa[2] = make_float4(acc[8],  acc[9],  acc[10], acc[11]);
        pa[3] = make_float4(acc[12], acc[13], acc[14], acc[15]);
    }
    #pragma unroll
    for (int d = 0; d < 16; ++d) {
        up[d] = fmaf(DT, vp[d], up[d]);
        up[d] = fmaf(E1, acc[d], up[d]);
        vp[d] = fmaf(E2, acc[d], vp[d]);
    }
}

// =====================================================================
// K1: chunk totals. Block 256 = 4 waves; wave w runs 4-step sub-chunk
// from zero, then in-block G^4 fold combines sub-totals. lane = batch.
// =====================================================================
__global__ __launch_bounds__(256) void phase1_k(const float* __restrict__ F,
                                                const float* ws_in,
                                                float* __restrict__ cbuf)
{
    __shared__ float sc[4][2048];
    __shared__ float pb[2][2048];
    const int tid = threadIdx.x;
    const int b = tid & 63;
    const int w = tid >> 6;
    const int k = blockIdx.x;
    float up[16], vp[16];
    #pragma unroll
    for (int d = 0; d < 16; ++d) { up[d] = 0.f; vp[d] = 0.f; }
    const int s0 = LCH * k + LSUB * w + 1;
    const int nst = min(LSUB, SEQ - s0);
    const float* Fb = F + (size_t)b * BSTRIDE + (size_t)s0 * ND;
    const uintptr_t wsa = (uintptr_t)ws_in;
    for (int i = 0; i < nst; ++i)
        newmark_step<false>(wsa, Fb + (size_t)i * ND, up, vp, nullptr, nullptr, nullptr);
    #pragma unroll
    for (int d = 0; d < 16; ++d) { sc[w][d*64 + b] = up[d]; sc[w][(16+d)*64 + b] = vp[d]; }
    __syncthreads();

    // fold: p = c0; p = G4*p + c_w  (w = 1..3)
    const int wr = __builtin_amdgcn_readfirstlane(tid >> 6);
    const uintptr_t g4a = (uintptr_t)(ws_in + WS_G4);
    float pr[8];
    #pragma unroll
    for (int q = 0; q < 8; ++q) { pr[q] = sc[0][(wr+4*q)*64 + b]; pb[0][(wr+4*q)*64 + b] = pr[q]; }
    __syncthreads();
    int cur = 0;
    for (int t = 1; t < 4; ++t) {
        uintptr_t gl = g4a; asm volatile("" : "+s"(gl));
        const float* __restrict__ G4 = (const float*)gl;
        float n[8];
        #pragma unroll
        for (int q = 0; q < 8; ++q) n[q] = sc[t][(wr+4*q)*64 + b];
        const float* prow = pb[cur];
        #pragma unroll
        for (int j = 0; j < 32; ++j) {
            const float pj = prow[j*64 + b];
            #pragma unroll
            for (int q = 0; q < 8; ++q) n[q] = fmaf(G4[(wr+4*q)*32 + j], pj, n[q]);
        }
        #pragma unroll
        for (int q = 0; q < 8; ++q) { pr[q] = n[q]; pb[cur^1][(wr+4*q)*64 + b] = n[q]; }
        cur ^= 1;
        __syncthreads();
    }
    #pragma unroll
    for (int q = 0; q < 8; ++q) cbuf[(size_t)k * 2048 + (wr+4*q)*64 + b] = pr[q];
}

// =====================================================================
// K2: affine scan  p' = Gm*p + c_k, software-pipelined c prefetch.
//  seed==null -> zero seed; totals!=null -> store final total;
//  totals==null -> store p into slot BEFORE update (in-place starts).
// =====================================================================
__global__ __launch_bounds__(256) void scan_k(const float* Gm_in,
                                              float* __restrict__ cbase,
                                              const float* __restrict__ seed,
                                              float* __restrict__ totals,
                                              int nIter)
{
    __shared__ float pb[2][2048];
    const int tid = threadIdx.x;
    const int b = tid & 63;
    const int w = __builtin_amdgcn_readfirstlane((int)(tid >> 6));
    const int g = blockIdx.x;
    const uintptr_t ga = (uintptr_t)Gm_in;
    float pr[8];
    #pragma unroll
    for (int q = 0; q < 8; ++q) {
        const int rrow = w + 4*q;
        pr[q] = seed ? seed[(size_t)g * 2048 + rrow*64 + b] : 0.f;
        pb[0][rrow*64 + b] = pr[q];
    }
    __syncthreads();
    int cur = 0;
    float* cslot = cbase + (size_t)g * nIter * 2048;
    float nq[8];
    #pragma unroll
    for (int q = 0; q < 8; ++q) nq[q] = cslot[(w + 4*q)*64 + b];
    for (int k = 0; k < nIter; ++k) {
        float nn[8];
        if (k + 1 < nIter) {
            #pragma unroll
            for (int q = 0; q < 8; ++q) nn[q] = cslot[2048 + (w + 4*q)*64 + b];
        }
        if (!totals) {
            #pragma unroll
            for (int q = 0; q < 8; ++q) cslot[(w + 4*q)*64 + b] = pr[q];
        }
        uintptr_t gl = ga; asm volatile("" : "+s"(gl));
        const float* __restrict__ Gm = (const float*)gl;
        float n[8];
        #pragma unroll
        for (int q = 0; q < 8; ++q) n[q] = nq[q];
        const float* prow = pb[cur];
        #pragma unroll
        for (int j = 0; j < 32; ++j) {
            const float pj = prow[j*64 + b];
            #pragma unroll
            for (int q = 0; q < 8; ++q) n[q] = fmaf(Gm[(w + 4*q)*32 + j], pj, n[q]);
        }
        #pragma unroll
        for (int q = 0; q < 8; ++q) { pr[q] = n[q]; pb[cur ^ 1][(w + 4*q)*64 + b] = n[q]; nq[q] = nn[q]; }
        cur ^= 1;
        cslot += 2048;
        __syncthreads();
    }
    if (totals) {
        #pragma unroll
        for (int q = 0; q < 8; ++q) totals[(size_t)g * 2048 + (w + 4*q)*64 + b] = pr[q];
    }
}

// =====================================================================
// K3: block j = sub-chunk (chunk k=j>>2, slot w=j&3). Warm-up 4w steps
// from the chunk start, then 4 output steps. 2048 blocks x 64.
// =====================================================================
__global__ __launch_bounds__(64) void phase3_k(const float* __restrict__ F,
                                               const float* ws_in,
                                               const float* __restrict__ starts,
                                               float* __restrict__ out)
{
    const int b = threadIdx.x;
    const int j = blockIdx.x;
    const int k = j >> 2, w = j & 3;
    float up[16], vp[16];
    const float* st = starts + (size_t)k * 2048;
    #pragma unroll
    for (int d = 0; d < 16; ++d) { up[d] = st[d*64 + b]; vp[d] = st[(16 + d)*64 + b]; }
    const int sbase = LCH * k + 1;
    const size_t fb = (size_t)b * BSTRIDE;
    const uintptr_t wsa = (uintptr_t)ws_in;
    const int nwarm = LSUB * w;
    for (int i = 0; i < nwarm; ++i)
        newmark_step<false>(wsa, F + fb + (size_t)(sbase + i) * ND, up, vp, nullptr, nullptr, nullptr);
    const int s0 = sbase + nwarm;
    const int nst = min(LSUB, SEQ - s0);
    for (int i = 0; i < nst; ++i) {
        const size_t off = fb + (size_t)(s0 + i) * ND;
        newmark_step<true>(wsa, F + off, up, vp,
                           out + UOFF + off, out + VOFF + off, out + AOFF + off);
    }
}

// =====================================================================
extern "C" void kernel_launch(void* const* d_in, const int* in_sizes, int n_in,
                              void* d_out, int out_size, void* d_ws, size_t ws_size,
                              hipStream_t stream)
{
    const float* F = (const float*)d_in[0];
    const float* M = (const float*)d_in[1];
    const float* C = (const float*)d_in[2];
    const float* K = (const float*)d_in[3];
    float* out = (float*)d_out;
    float* ws  = (float*)d_ws;

    setup_k <<<1,     512, 0, stream>>>(F, M, C, K, ws, out);
    phase1_k<<<NCH,   256, 0, stream>>>(F, ws, ws + WS_C);
    // scan hierarchy: 512 chunks = 64 groups x 8; 64 groups = 8 supers x 8
    scan_k  <<<64,    256, 0, stream>>>(ws + WS_G16,   ws + WS_C,  nullptr,     ws + WS_GT, 8);
    scan_k  <<<8,     256, 0, stream>>>(ws + WS_G128,  ws + WS_GT, nullptr,     ws + WS_ST, 8);
    scan_k  <<<1,     256, 0, stream>>>(ws + WS_G1024, ws + WS_ST, ws + WS_P1,  nullptr,    8);
    scan_k  <<<8,     256, 0, stream>>>(ws + WS_G128,  ws + WS_GT, ws + WS_ST,  nullptr,    8);
    scan_k  <<<64,    256, 0, stream>>>(ws + WS_G16,   ws + WS_C,  ws + WS_GT,  nullptr,    8);
    phase3_k<<<NCH*4, 64,  0, stream>>>(F, ws, ws + WS_C, out);
}

// Round 3
// 510.979 us; speedup vs baseline: 1.1835x; 1.1198x over previous
//
#include <hip/hip_runtime.h>
#include <hip/hip_bf16.h>
#include <stdint.h>

// ---------------- problem constants ----------------
constexpr int   SEQ  = 8192;
constexpr int   NB   = 64;
constexpr int   ND   = 16;
constexpr float DT    = 0.01f;
constexpr float BETA  = 0.25f;
constexpr float GAMMA = 0.5f;
constexpr float C1 = (0.5f - BETA) * DT * DT;
constexpr float C2 = (1.0f - GAMMA) * DT;
constexpr float C3 = BETA * DT * DT;
constexpr float C4 = GAMMA * DT;
constexpr float E1 = C1 + C3 + DT * C4;
constexpr float E2 = C2 + C4;
constexpr float GDT  = GAMMA * DT;
constexpr float BDT2 = BETA * DT * DT;

constexpr int LSUB = 4;      // sub-chunk
constexpr int LCH  = 16;     // chunk (scan granularity)
constexpr int NCH  = 512;    // chunks
constexpr size_t BSTRIDE = (size_t)SEQ * ND;
constexpr size_t UOFF = 0;
constexpr size_t VOFF = (size_t)NB * SEQ * ND;
constexpr size_t AOFF = 2 * VOFF;

// ws layout (float offsets)
constexpr int WS_A1T   = 0;       // 256 (transposed)
constexpr int WS_A2T   = 256;
constexpr int WS_A3T   = 512;
constexpr int WS_G4    = 768;     // 1024 each, row-major 32x32
constexpr int WS_G16   = 1792;
constexpr int WS_G128  = 2816;
constexpr int WS_G1024 = 3840;
constexpr int WS_P1    = 4864;    // 2048
constexpr int WS_ST    = 6912;    // 8   * 2048
constexpr int WS_GT    = 23296;   // 64  * 2048
constexpr int WS_C     = 154368;  // 512 * 2048 chunk totals -> starts

// =====================================================================
// K0: invert K_eff & M, A2/A3, G powers, p1 seed, step-0 outputs.
// =====================================================================
__global__ __launch_bounds__(512) void setup_k(const float* __restrict__ F,
                                               const float* __restrict__ Mg,
                                               const float* __restrict__ Cg,
                                               const float* __restrict__ Kg,
                                               float* __restrict__ ws,
                                               float* __restrict__ out)
{
    __shared__ float sM[256], sC[256], sK[256];
    __shared__ float aug[16][33];
    __shared__ float A1s[256], A2s[256], A3s[256], Mis[256];
    __shared__ float bA[1024], bB[1024];
    const int tid = threadIdx.x;
    if (tid < 256) { sM[tid] = Mg[tid]; sC[tid] = Cg[tid]; sK[tid] = Kg[tid]; }
    __syncthreads();

    const int r = tid >> 5, c = tid & 31;
    {
        float v;
        if (c < 16) v = sM[r*16+c] + GDT * sC[r*16+c] + BDT2 * sK[r*16+c];
        else        v = (c - 16 == r) ? 1.f : 0.f;
        aug[r][c] = v;
    }
    __syncthreads();
    for (int kk = 0; kk < 16; ++kk) {
        float pv   = aug[kk][kk];
        float fr   = aug[r][kk];
        float akc  = aug[kk][c];
        float curv = aug[r][c];
        __syncthreads();
        float inv = 1.0f / pv;
        aug[r][c] = (r == kk) ? curv * inv : fmaf(-fr * inv, akc, curv);
        __syncthreads();
    }
    if (tid < 256) A1s[tid] = aug[tid >> 4][(tid & 15) + 16];
    __syncthreads();

    aug[r][c] = (c < 16) ? sM[r*16+c] : ((c - 16 == r) ? 1.f : 0.f);
    __syncthreads();
    for (int kk = 0; kk < 16; ++kk) {
        float pv   = aug[kk][kk];
        float fr   = aug[r][kk];
        float akc  = aug[kk][c];
        float curv = aug[r][c];
        __syncthreads();
        float inv = 1.0f / pv;
        aug[r][c] = (r == kk) ? curv * inv : fmaf(-fr * inv, akc, curv);
        __syncthreads();
    }
    if (tid < 256) Mis[tid] = aug[tid >> 4][(tid & 15) + 16];
    __syncthreads();

    if (tid < 256) {
        const int rr = tid >> 4, cc = tid & 15;
        float a2 = 0.f, a3 = 0.f;
        #pragma unroll
        for (int j = 0; j < 16; ++j) {
            const float a = A1s[rr*16+j];
            a2 = fmaf(a, sC[j*16+cc], a2);
            a3 = fmaf(a, sK[j*16+cc], a3);
        }
        A2s[tid] = a2; A3s[tid] = a3;
    }
    __syncthreads();

    if (tid < 256) {
        const int j = tid >> 4, d = tid & 15;
        ws[WS_A1T + tid] = A1s[d*16+j];
        ws[WS_A2T + tid] = A2s[d*16+j];
        ws[WS_A3T + tid] = A3s[d*16+j];
    }
    for (int idx = tid; idx < 1024; idx += 512) {
        const int i = idx >> 5, j = idx & 31;
        float v;
        if (i < 16) {
            if (j < 16) v = ((i == j) ? 1.f : 0.f) - E1 * A3s[i*16+j];
            else        v = ((i == j - 16) ? DT : 0.f) - E1 * A2s[i*16+(j-16)];
        } else {
            const int i2 = i - 16;
            if (j < 16) v = -E2 * A3s[i2*16+j];
            else        v = ((i2 == j - 16) ? 1.f : 0.f) - E2 * A2s[i2*16+(j-16)];
        }
        bA[idx] = v;
    }
    __syncthreads();
    for (int s = 0; s < 10; ++s) {
        for (int idx = tid; idx < 1024; idx += 512) {
            const int i = idx >> 5, j = idx & 31;
            float acc = 0.f;
            #pragma unroll
            for (int q = 0; q < 32; ++q) acc = fmaf(bA[i*32+q], bA[q*32+j], acc);
            bB[idx] = acc;
        }
        __syncthreads();
        for (int idx = tid; idx < 1024; idx += 512) bA[idx] = bB[idx];
        __syncthreads();
        if (s == 1) for (int idx = tid; idx < 1024; idx += 512) ws[WS_G4   + idx] = bA[idx];
        if (s == 3) for (int idx = tid; idx < 1024; idx += 512) ws[WS_G16  + idx] = bA[idx];
        if (s == 6) for (int idx = tid; idx < 1024; idx += 512) ws[WS_G128 + idx] = bA[idx];
    }
    for (int idx = tid; idx < 1024; idx += 512) ws[WS_G1024 + idx] = bA[idx];

    for (int t = tid; t < 1024; t += 512) {
        const int b = t >> 4, d = t & 15;
        float s0 = 0.f;
        #pragma unroll
        for (int j = 0; j < 16; ++j) s0 = fmaf(Mis[d*16+j], F[(size_t)b * BSTRIDE + j], s0);
        out[UOFF + (size_t)b * BSTRIDE + d] = 0.f;
        out[VOFF + (size_t)b * BSTRIDE + d] = 0.f;
        out[AOFF + (size_t)b * BSTRIDE + d] = s0;
        ws[WS_P1 + d*64 + b]        = C1 * s0;
        ws[WS_P1 + (16 + d)*64 + b] = C2 * s0;
    }
}

// ---------------------------------------------------------------------
// Stage one 8-step half of a chunk's F tile into LDS (XOR-swizzled).
// sF layout: sF[b*128 + (W ^ (b&31))], W = s_in_half*16 + d.
// Coalesced: each wave loads 2 batches x 512 B contiguous per pass.
// ---------------------------------------------------------------------
__device__ __forceinline__ void stage_half(const float* __restrict__ F, float* __restrict__ sF,
                                           int l, int w, int s0, int nst, int h)
{
    const int lw  = l & 31;
    const int sin = lw >> 2;                      // step within half
    const bool valid = (8*h + sin) < nst;
    const int W0 = 4*lw;
    #pragma unroll
    for (int p = 0; p < 8; ++p) {
        const int b = p*8 + w*2 + (l >> 5);
        float4 x = make_float4(0.f,0.f,0.f,0.f);
        if (valid) x = *(const float4*)(F + (size_t)b * BSTRIDE + (size_t)(s0 + 8*h) * ND + W0);
        const int c = b & 31;
        sF[b*128 + ((W0+0) ^ c)] = x.x;
        sF[b*128 + ((W0+1) ^ c)] = x.y;
        sF[b*128 + ((W0+2) ^ c)] = x.z;
        sF[b*128 + ((W0+3) ^ c)] = x.w;
    }
}

// ---------------------------------------------------------------------
// One Newmark step; F from LDS (lane = batch), matrices via s_load
// (anti-LICM reload each step to avoid register blowup).
// ---------------------------------------------------------------------
__device__ __forceinline__ void newmark_step_lds(uintptr_t wsa, const float* __restrict__ sF,
                                                 int l, int sin,
                                                 float up[16], float vp[16], float acc[16])
{
    uintptr_t wsl = wsa;
    asm volatile("" : "+s"(wsl));
    const float* __restrict__ A1t = (const float*)wsl;
    const float* __restrict__ A2t = A1t + 256;
    const float* __restrict__ A3t = A1t + 512;
    const int c = l & 31;
    const int base = l*128 + 0;
    float f[16];
    #pragma unroll
    for (int d = 0; d < 16; ++d) f[d] = sF[base + ((sin*16 + d) ^ c)];
    #pragma unroll
    for (int d = 0; d < 16; ++d) acc[d] = 0.f;
    #pragma unroll
    for (int j = 0; j < 16; ++j) {
        const float fj = f[j], nu = -up[j], nv = -vp[j];
        #pragma unroll
        for (int d = 0; d < 16; ++d) {
            acc[d] = fmaf(A1t[j*16+d], fj, acc[d]);
            acc[d] = fmaf(A3t[j*16+d], nu, acc[d]);
            acc[d] = fmaf(A2t[j*16+d], nv, acc[d]);
        }
    }
    #pragma unroll
    for (int d = 0; d < 16; ++d) {
        up[d] = fmaf(DT, vp[d], up[d]);
        up[d] = fmaf(E1, acc[d], up[d]);
        vp[d] = fmaf(E2, acc[d], vp[d]);
    }
}

// =====================================================================
// K1: chunk totals. 512 blocks x 256 thr. F staged in halves; wave w
// computes 4-step sub-total t_w from zero; G4 fold -> chunk total.
// =====================================================================
__global__ __launch_bounds__(256, 2) void phase1_k(const float* __restrict__ F,
                                                   const float* ws_in,
                                                   float* __restrict__ cbuf)
{
    __shared__ float sF[64*128];    // 32 KB
    __shared__ float st[4][2048];   // 32 KB sub-totals / fold buffers
    const int tid = threadIdx.x;
    const int l = tid & 63;
    const int w = tid >> 6;
    const int k = blockIdx.x;
    const int s0 = LCH * k + 1;
    const int nst = min(LCH, SEQ - s0);
    const uintptr_t wsa = (uintptr_t)ws_in;

    float up[16], vp[16], acc[16];
    #pragma unroll
    for (int d = 0; d < 16; ++d) { up[d] = 0.f; vp[d] = 0.f; }

    stage_half(F, sF, l, w, s0, nst, 0);
    __syncthreads();
    if (w < 2) {
        #pragma unroll
        for (int i = 0; i < 4; ++i) {
            const int ls = 4*w + i;
            newmark_step_lds(wsa, sF, l, ls & 7, up, vp, acc);
        }
        #pragma unroll
        for (int d = 0; d < 16; ++d) { st[w][d*64 + l] = up[d]; st[w][(16+d)*64 + l] = vp[d]; }
    }
    __syncthreads();
    stage_half(F, sF, l, w, s0, nst, 1);
    __syncthreads();
    if (w >= 2) {
        #pragma unroll
        for (int i = 0; i < 4; ++i) {
            const int ls = 4*w + i;
            if (ls < nst) newmark_step_lds(wsa, sF, l, ls & 7, up, vp, acc);
        }
        #pragma unroll
        for (int d = 0; d < 16; ++d) { st[w][d*64 + l] = up[d]; st[w][(16+d)*64 + l] = vp[d]; }
    }
    __syncthreads();

    // fold: cum = st[0]; st[r] <- G4*cum + st[r]  (cum = st[r-1])
    const int wr = __builtin_amdgcn_readfirstlane(tid >> 6);
    const uintptr_t g4a = (uintptr_t)(ws_in + WS_G4);
    float n[8];
    for (int r = 1; r < 4; ++r) {
        uintptr_t gl = g4a; asm volatile("" : "+s"(gl));
        const float* __restrict__ G4 = (const float*)gl;
        #pragma unroll
        for (int q = 0; q < 8; ++q) n[q] = st[r][(wr+4*q)*64 + l];
        #pragma unroll
        for (int j = 0; j < 32; ++j) {
            const float pj = st[r-1][j*64 + l];
            #pragma unroll
            for (int q = 0; q < 8; ++q) n[q] = fmaf(G4[(wr+4*q)*32 + j], pj, n[q]);
        }
        if (r < 3) {
            #pragma unroll
            for (int q = 0; q < 8; ++q) st[r][(wr+4*q)*64 + l] = n[q];
            __syncthreads();
        }
    }
    #pragma unroll
    for (int q = 0; q < 8; ++q) cbuf[(size_t)k * 2048 + (wr+4*q)*64 + l] = n[q];
}

// =====================================================================
// K2: affine scan  p' = Gm*p + c_k (unchanged from R1).
// =====================================================================
__global__ __launch_bounds__(256) void scan_k(const float* Gm_in,
                                              float* __restrict__ cbase,
                                              const float* __restrict__ seed,
                                              float* __restrict__ totals,
                                              int nIter)
{
    __shared__ float pb[2][2048];
    const int tid = threadIdx.x;
    const int b = tid & 63;
    const int w = __builtin_amdgcn_readfirstlane((int)(tid >> 6));
    const int g = blockIdx.x;
    const uintptr_t ga = (uintptr_t)Gm_in;
    float pr[8];
    #pragma unroll
    for (int q = 0; q < 8; ++q) {
        const int rrow = w + 4*q;
        pr[q] = seed ? seed[(size_t)g * 2048 + rrow*64 + b] : 0.f;
        pb[0][rrow*64 + b] = pr[q];
    }
    __syncthreads();
    int cur = 0;
    float* cslot = cbase + (size_t)g * nIter * 2048;
    float nq[8];
    #pragma unroll
    for (int q = 0; q < 8; ++q) nq[q] = cslot[(w + 4*q)*64 + b];
    for (int k = 0; k < nIter; ++k) {
        float nn[8];
        if (k + 1 < nIter) {
            #pragma unroll
            for (int q = 0; q < 8; ++q) nn[q] = cslot[2048 + (w + 4*q)*64 + b];
        }
        if (!totals) {
            #pragma unroll
            for (int q = 0; q < 8; ++q) cslot[(w + 4*q)*64 + b] = pr[q];
        }
        uintptr_t gl = ga; asm volatile("" : "+s"(gl));
        const float* __restrict__ Gm = (const float*)gl;
        float n[8];
        #pragma unroll
        for (int q = 0; q < 8; ++q) n[q] = nq[q];
        const float* prow = pb[cur];
        #pragma unroll
        for (int j = 0; j < 32; ++j) {
            const float pj = prow[j*64 + b];
            #pragma unroll
            for (int q = 0; q < 8; ++q) n[q] = fmaf(Gm[(w + 4*q)*32 + j], pj, n[q]);
        }
        #pragma unroll
        for (int q = 0; q < 8; ++q) { pr[q] = n[q]; pb[cur ^ 1][(w + 4*q)*64 + b] = n[q]; nq[q] = nn[q]; }
        cur ^= 1;
        cslot += 2048;
        __syncthreads();
    }
    if (totals) {
        #pragma unroll
        for (int q = 0; q < 8; ++q) totals[(size_t)g * 2048 + (w + 4*q)*64 + b] = pr[q];
    }
}

// ---------------------------------------------------------------------
// Drain one array's 4-step group from LDS to global (256 B per batch).
// so layout: so[b*64 + (e ^ (b&31))], e = i*16 + d  (i = step in group).
// ---------------------------------------------------------------------
__device__ __forceinline__ void drain_arr(const float* __restrict__ so_w,
                                          float* __restrict__ gbase,
                                          int l, int w, int nst)
{
    const int m = l & 15, dlt = l >> 4;
    const bool ok = (4*w + (m >> 2)) < nst;
    #pragma unroll
    for (int g = 0; g < 16; ++g) {
        const int b = g*4 + dlt;
        const int cb = b & 31;
        float4 x;
        x.x = so_w[b*64 + ((4*m+0) ^ cb)];
        x.y = so_w[b*64 + ((4*m+1) ^ cb)];
        x.z = so_w[b*64 + ((4*m+2) ^ cb)];
        x.w = so_w[b*64 + ((4*m+3) ^ cb)];
        if (ok) *(float4*)(gbase + (size_t)b * BSTRIDE + 4*m) = x;
    }
}

// =====================================================================
// K3: outputs. 512 blocks x 256 thr. Warm-up ladder 0/4/8/12 across the
// 4 waves; F staged in halves; outputs staged in LDS, drained as 256 B
// bursts; v,a kept in registers during the u drain.
// =====================================================================
__global__ __launch_bounds__(256, 2) void phase3_k(const float* __restrict__ F,
                                                   const float* ws_in,
                                                   const float* __restrict__ starts,
                                                   float* __restrict__ out)
{
    __shared__ float sF[64*128];     // 32 KB
    __shared__ float so[2][4096];    // 32 KB: 2 concurrent waves' out staging
    const int tid = threadIdx.x;
    const int l = tid & 63;
    const int w = tid >> 6;
    const int k = blockIdx.x;
    const int s0 = LCH * k + 1;
    const int nst = min(LCH, SEQ - s0);
    const uintptr_t wsa = (uintptr_t)ws_in;

    float up[16], vp[16], acc[16];
    const float* stt = starts + (size_t)k * 2048;
    #pragma unroll
    for (int d = 0; d < 16; ++d) { up[d] = stt[d*64 + l]; vp[d] = stt[(16+d)*64 + l]; }

    float vo[4][16], ao[4][16];
    float* so_w = &so[w & 1][0];
    const int c = l & 31;
    const int gbase_s = s0 + 4*w;

    stage_half(F, sF, l, w, s0, nst, 0);
    __syncthreads();

    if (w < 2) {
        // warm-up (wave1: steps 0-3), then outputs 4w..4w+3
        for (int i = 0; i < 4*w; ++i)
            newmark_step_lds(wsa, sF, l, i & 7, up, vp, acc);
        #pragma unroll
        for (int i = 0; i < 4; ++i) {
            const int ls = 4*w + i;
            newmark_step_lds(wsa, sF, l, ls & 7, up, vp, acc);
            // note: up/vp were updated; reconstruct outputs from pre-update state:
            // u_n = up_old + C3*acc ; up_new = up_old + DT*vp_old + E1*acc
            // easier: recompute from post-state: u_n = up_new - DT*vp_old - (E1-C3)*acc ... instead
            // we store outputs computed before update inside the step below.
            // (handled by storing from acc + saved pre-state)
            #pragma unroll
            for (int d = 0; d < 16; ++d) {
                // pre-update state: up_old = up - DT*vp_old - E1*acc; vp_old = vp - E2*acc
                const float vpo = vp[d] - E2*acc[d];
                const float upo = up[d] - DT*vpo - E1*acc[d];
                so_w[l*64 + ((i*16+d) ^ c)] = fmaf(C3, acc[d], upo);
                vo[i][d] = fmaf(C4, acc[d], vpo);
                ao[i][d] = acc[d];
            }
        }
        drain_arr(so_w, out + UOFF + (size_t)gbase_s * ND, l, w, nst);
        #pragma unroll
        for (int i = 0; i < 4; ++i)
            #pragma unroll
            for (int d = 0; d < 16; ++d) so_w[l*64 + ((i*16+d) ^ c)] = vo[i][d];
        drain_arr(so_w, out + VOFF + (size_t)gbase_s * ND, l, w, nst);
        #pragma unroll
        for (int i = 0; i < 4; ++i)
            #pragma unroll
            for (int d = 0; d < 16; ++d) so_w[l*64 + ((i*16+d) ^ c)] = ao[i][d];
        drain_arr(so_w, out + AOFF + (size_t)gbase_s * ND, l, w, nst);
    } else {
        // waves 2,3: warm through steps 0-7
        for (int i = 0; i < 8; ++i)
            newmark_step_lds(wsa, sF, l, i & 7, up, vp, acc);
    }
    __syncthreads();
    stage_half(F, sF, l, w, s0, nst, 1);
    __syncthreads();

    if (w >= 2) {
        if (w == 3) {
            for (int i = 8; i < 12; ++i)
                newmark_step_lds(wsa, sF, l, i & 7, up, vp, acc);
        }
        #pragma unroll
        for (int i = 0; i < 4; ++i) {
            const int ls = 4*w + i;
            if (ls < nst) {
                newmark_step_lds(wsa, sF, l, ls & 7, up, vp, acc);
                #pragma unroll
                for (int d = 0; d < 16; ++d) {
                    const float vpo = vp[d] - E2*acc[d];
                    const float upo = up[d] - DT*vpo - E1*acc[d];
                    so_w[l*64 + ((i*16+d) ^ c)] = fmaf(C3, acc[d], upo);
                    vo[i][d] = fmaf(C4, acc[d], vpo);
                    ao[i][d] = acc[d];
                }
            }
        }
        drain_arr(so_w, out + UOFF + (size_t)gbase_s * ND, l, w, nst);
        #pragma unroll
        for (int i = 0; i < 4; ++i)
            #pragma unroll
            for (int d = 0; d < 16; ++d) so_w[l*64 + ((i*16+d) ^ c)] = vo[i][d];
        drain_arr(so_w, out + VOFF + (size_t)gbase_s * ND, l, w, nst);
        #pragma unroll
        for (int i = 0; i < 4; ++i)
            #pragma unroll
            for (int d = 0; d < 16; ++d) so_w[l*64 + ((i*16+d) ^ c)] = ao[i][d];
        drain_arr(so_w, out + AOFF + (size_t)gbase_s * ND, l, w, nst);
    }
}

// =====================================================================
extern "C" void kernel_launch(void* const* d_in, const int* in_sizes, int n_in,
                              void* d_out, int out_size, void* d_ws, size_t ws_size,
                              hipStream_t stream)
{
    const float* F = (const float*)d_in[0];
    const float* M = (const float*)d_in[1];
    const float* C = (const float*)d_in[2];
    const float* K = (const float*)d_in[3];
    float* out = (float*)d_out;
    float* ws  = (float*)d_ws;

    setup_k <<<1,   512, 0, stream>>>(F, M, C, K, ws, out);
    phase1_k<<<NCH, 256, 0, stream>>>(F, ws, ws + WS_C);
    scan_k  <<<64,  256, 0, stream>>>(ws + WS_G16,   ws + WS_C,  nullptr,     ws + WS_GT, 8);
    scan_k  <<<8,   256, 0, stream>>>(ws + WS_G128,  ws + WS_GT, nullptr,     ws + WS_ST, 8);
    scan_k  <<<1,   256, 0, stream>>>(ws + WS_G1024, ws + WS_ST, ws + WS_P1,  nullptr,    8);
    scan_k  <<<8,   256, 0, stream>>>(ws + WS_G128,  ws + WS_GT, ws + WS_ST,  nullptr,    8);
    scan_k  <<<64,  256, 0, stream>>>(ws + WS_G16,   ws + WS_C,  ws + WS_GT,  nullptr,    8);
    phase3_k<<<NCH, 256, 0, stream>>>(F, ws, ws + WS_C, out);
}